// Round 5
// baseline (457.234 us; speedup 1.0000x reference)
//
#include <hip/hip_runtime.h>
#include <hip/hip_bf16.h>
#include <stdint.h>

#define HIDDEN 1024
#define TOKENS 32768
#define NE 8
#define BK2 32

typedef unsigned short u16;
typedef short bf16x8 __attribute__((ext_vector_type(8)));
typedef float f32x4 __attribute__((ext_vector_type(4)));
typedef unsigned u32x4 __attribute__((ext_vector_type(4)));

__device__ __forceinline__ void gload_lds16(const void* g, void* l) {
  __builtin_amdgcn_global_load_lds(
      (const __attribute__((address_space(1))) void*)g,
      (__attribute__((address_space(3))) void*)l, 16, 0, 0);
}

// ============ kA: fused prep kernel (grid-split) ============
// blocks [0,1024): gating (fp32) -> s[tok]; emit Abf (bf16 H).
// blocks [1024,1280): W transpose+convert -> Bt; block 1024 zeroes cnt[].
__global__ __launch_bounds__(512) void kA(const float* __restrict__ H,
                                          const float* __restrict__ G,
                                          const float* __restrict__ W,
                                          float* __restrict__ s,
                                          u16* __restrict__ Bt,
                                          u16* __restrict__ Abf,
                                          int* __restrict__ cnt) {
  __shared__ float shf[NE * HIDDEN];  // 32 KiB (k1 Gs; k0 uses first 4160)
  const int t = threadIdx.x;

  if (blockIdx.x >= 1024) {
    // ---- k0 part: W [h][d] fp32 -> Bt [d][h] bf16
    const int bx = blockIdx.x - 1024;
    if (bx == 0 && t < 128) cnt[t] = 0;
    const int d0 = (bx & 15) * 64;
    const int h0 = (bx >> 4) * 64;
#pragma unroll
    for (int p = 0; p < 8; ++p) {
      int idx = p * 512 + t;
      int r = idx >> 6, c = idx & 63;
      shf[r * 65 + c] = W[(size_t)(h0 + r) * HIDDEN + d0 + c];
    }
    __syncthreads();
#pragma unroll
    for (int p = 0; p < 8; ++p) {
      int idx = p * 512 + t;
      int r = idx >> 6, c = idx & 63;
      __hip_bfloat16 v = __float2bfloat16(shf[c * 65 + r]);
      Bt[(size_t)(d0 + r) * HIDDEN + h0 + c] = *(u16*)&v;
    }
    return;
  }

  // ---- k1 part: gating + Abf emit
#pragma unroll
  for (int i = 0; i < 4; ++i)
    ((float4*)shf)[i * 512 + t] = ((const float4*)G)[i * 512 + t];
  __syncthreads();

  const int lane = t & 63;
  const int wave = t >> 6;
  const int tok0 = (blockIdx.x * 8 + wave) * 4;

#pragma unroll
  for (int tp = 0; tp < 2; ++tp) {
    const int tok = tok0 + tp * 2;
    const float* h0p = H + (size_t)tok * HIDDEN;
    const float* h1p = h0p + HIDDEN;
    float4 h0[4], h1[4];
#pragma unroll
    for (int p = 0; p < 4; ++p) {
      h0[p] = *(const float4*)(h0p + p * 256 + lane * 4);
      h1[p] = *(const float4*)(h1p + p * 256 + lane * 4);
    }
#pragma unroll
    for (int p = 0; p < 4; ++p) {
      __hip_bfloat162 lo0 = __float22bfloat162_rn(make_float2(h0[p].x, h0[p].y));
      __hip_bfloat162 hi0 = __float22bfloat162_rn(make_float2(h0[p].z, h0[p].w));
      uint2 pk0;
      pk0.x = *(unsigned*)&lo0;
      pk0.y = *(unsigned*)&hi0;
      *(uint2*)(Abf + (size_t)tok * HIDDEN + p * 256 + lane * 4) = pk0;
      __hip_bfloat162 lo1 = __float22bfloat162_rn(make_float2(h1[p].x, h1[p].y));
      __hip_bfloat162 hi1 = __float22bfloat162_rn(make_float2(h1[p].z, h1[p].w));
      uint2 pk1;
      pk1.x = *(unsigned*)&lo1;
      pk1.y = *(unsigned*)&hi1;
      *(uint2*)(Abf + (size_t)(tok + 1) * HIDDEN + p * 256 + lane * 4) = pk1;
    }

    float a0[NE], a1[NE];
#pragma unroll
    for (int e = 0; e < NE; ++e) { a0[e] = 0.f; a1[e] = 0.f; }
#pragma unroll
    for (int p = 0; p < 4; ++p)
#pragma unroll
      for (int e = 0; e < NE; ++e) {
        float4 w = *(const float4*)&shf[e * HIDDEN + p * 256 + lane * 4];
        a0[e] += h0[p].x * w.x + h0[p].y * w.y + h0[p].z * w.z + h0[p].w * w.w;
        a1[e] += h1[p].x * w.x + h1[p].y * w.y + h1[p].z * w.z + h1[p].w * w.w;
      }
#pragma unroll
    for (int st = 1; st <= 4; st <<= 1)
#pragma unroll
      for (int e = 0; e < NE; ++e) {
        a0[e] += __shfl_xor(a0[e], st, 64);
        a1[e] += __shfl_xor(a1[e], st, 64);
      }
    const bool b0 = lane & 1, b1 = lane & 2, b2 = lane & 4;
    float t01 = b0 ? a0[1] : a0[0], t23 = b0 ? a0[3] : a0[2];
    float t45 = b0 ? a0[5] : a0[4], t67 = b0 ? a0[7] : a0[6];
    float u03 = b1 ? t23 : t01, u47 = b1 ? t67 : t45;
    float v0 = b2 ? u47 : u03;
    float s01 = b0 ? a1[1] : a1[0], s23 = b0 ? a1[3] : a1[2];
    float s45 = b0 ? a1[5] : a1[4], s67 = b0 ? a1[7] : a1[6];
    float w03 = b1 ? s23 : s01, w47 = b1 ? s67 : s45;
    float v1 = b2 ? w47 : w03;
    v0 += __shfl_xor(v0, 8, 64);
    v0 += __shfl_xor(v0, 16, 64);
    v0 += __shfl_xor(v0, 32, 64);
    v1 += __shfl_xor(v1, 8, 64);
    v1 += __shfl_xor(v1, 16, 64);
    v1 += __shfl_xor(v1, 32, 64);
    float m1a = v0, m2a = -3.0e38f, m1b = v1, m2b = -3.0e38f;
#pragma unroll
    for (int st = 1; st <= 4; st <<= 1) {
      float o1 = __shfl_xor(m1a, st, 64);
      float o2 = __shfl_xor(m2a, st, 64);
      float lo = fminf(m1a, o1);
      m1a = fmaxf(m1a, o1);
      m2a = fmaxf(lo, fmaxf(m2a, o2));
      float p1 = __shfl_xor(m1b, st, 64);
      float p2 = __shfl_xor(m2b, st, 64);
      float lo2 = fminf(m1b, p1);
      m1b = fmaxf(m1b, p1);
      m2b = fmaxf(lo2, fmaxf(m2b, p2));
    }
    if (lane == 0) {
      s[tok] = m1a + m2a;
      s[tok + 1] = m1b + m2b;
    }
  }
}

// ============ kB: GEMM (R2-exact core) + elected per-panel LayerNorm ============
__global__ __launch_bounds__(512, 2) void kB(const u16* __restrict__ A,
                                             const u16* __restrict__ Bt,
                                             const float* __restrict__ s,
                                             const float* __restrict__ gamma,
                                             const float* __restrict__ beta,
                                             u16* __restrict__ C,
                                             float* __restrict__ out,
                                             int* __restrict__ cnt,
                                             int fuse) {
  __shared__ u16 smem[2 * 2 * 8192];  // 64 KiB
  __shared__ int elect;
  const int t = threadIdx.x;
  const int lane = t & 63;
  const int wave = t >> 6;

  const int b = blockIdx.x;
  const int tile = (b & 7) * 64 + (b >> 3);
  const int m0 = (tile >> 2) * 256;
  const int n0 = (tile & 3) * 256;

  const int wm = (wave >> 2) * 128;
  const int wn = (wave & 3) * 64;
  const int lm = lane & 15;
  const int lq = lane >> 4;

  const int r0 = t >> 2, r1 = (512 + t) >> 2;
  const int q0 = (t & 3) ^ ((r0 ^ (r0 >> 2)) & 3);
  const int q1 = (t & 3) ^ ((r1 ^ (r1 >> 2)) & 3);
  const u16* gA0 = A + (size_t)(m0 + r0) * HIDDEN + q0 * 8;
  const u16* gA1 = A + (size_t)(m0 + r1) * HIDDEN + q1 * 8;
  const u16* gB0 = Bt + (size_t)(n0 + r0) * HIDDEN + q0 * 8;
  const u16* gB1 = Bt + (size_t)(n0 + r1) * HIDDEN + q1 * 8;
  const int lds0 = t * 8;
  const int lds1 = (512 + t) * 8;

  f32x4 acc[8][4];
#pragma unroll
  for (int i = 0; i < 8; ++i)
#pragma unroll
    for (int j = 0; j < 4; ++j) acc[i][j] = (f32x4){0.f, 0.f, 0.f, 0.f};

#define STAGE(buf, kk)                                   \
  do {                                                   \
    u16* base_ = smem + (buf) * 16384;                   \
    gload_lds16(gA0 + (kk), base_ + lds0);               \
    gload_lds16(gA1 + (kk), base_ + lds1);               \
    gload_lds16(gB0 + (kk), base_ + 8192 + lds0);        \
    gload_lds16(gB1 + (kk), base_ + 8192 + lds1);        \
  } while (0)

  STAGE(0, 0);
  STAGE(1, BK2);
  asm volatile("s_waitcnt vmcnt(4)" ::: "memory");
  asm volatile("s_barrier" ::: "memory");

  int cur = 0;
  for (int tt = 0; tt < 32; ++tt) {
    const u16* As = smem + cur * 16384;
    const u16* Bs = As + 8192;
    bf16x8 af[8], bfr[4];
#pragma unroll
    for (int i = 0; i < 8; ++i) {
      int r = wm + i * 16 + lm;
      int qs = lq ^ ((r ^ (r >> 2)) & 3);
      af[i] = *(const bf16x8*)&As[(r * 4 + qs) * 8];
    }
#pragma unroll
    for (int j = 0; j < 4; ++j) {
      int r = wn + j * 16 + lm;
      int qs = lq ^ ((r ^ (r >> 2)) & 3);
      bfr[j] = *(const bf16x8*)&Bs[(r * 4 + qs) * 8];
    }
    __builtin_amdgcn_s_setprio(1);
#pragma unroll
    for (int i = 0; i < 8; ++i)
#pragma unroll
      for (int j = 0; j < 4; ++j)
        acc[i][j] = __builtin_amdgcn_mfma_f32_16x16x32_bf16(af[i], bfr[j], acc[i][j], 0, 0, 0);
    __builtin_amdgcn_s_setprio(0);
    asm volatile("s_waitcnt lgkmcnt(0)" ::: "memory");
    asm volatile("s_barrier" ::: "memory");
    if (tt + 2 < 32) {
      STAGE(cur, (tt + 2) * BK2);
      asm volatile("s_waitcnt vmcnt(4)" ::: "memory");
    } else {
      asm volatile("s_waitcnt vmcnt(0)" ::: "memory");
    }
    asm volatile("s_barrier" ::: "memory");
    cur ^= 1;
  }
#undef STAGE

#pragma unroll
  for (int i = 0; i < 8; ++i) {
#pragma unroll
    for (int rr = 0; rr < 4; ++rr) {
      int row = m0 + wm + i * 16 + lq * 4 + rr;
      size_t base = (size_t)row * HIDDEN + n0 + wn + lm;
#pragma unroll
      for (int j = 0; j < 4; ++j) {
        __hip_bfloat16 v = __float2bfloat16(acc[i][j][rr]);
        C[base + j * 16] = *(u16*)&v;
      }
    }
  }

  if (!fuse) return;

  // ---- election: last of the 4 n-blocks of this m-panel runs LN
  __syncthreads();  // vmcnt(0) drain => all C stores of this block complete
  if (t == 0) {
    __threadfence();  // release (wbl2): C visible device-wide
    elect = (atomicAdd(&cnt[m0 >> 8], 1) == 3) ? 1 : 0;
  }
  __syncthreads();
  if (!elect) return;
  __threadfence();  // acquire (inv): no stale C lines in this XCD's caches

  // ---- LayerNorm over the panel's 256 full rows; 8 waves x 32 rows
  for (int rr = 0; rr < 32; ++rr) {
    const int tok = m0 + wave * 32 + rr;
    const float sc = s[tok];
    const u32x4* row = (const u32x4*)(C + (size_t)tok * HIDDEN);
    float x[16];
    float sum = 0.f, sq = 0.f;
#pragma unroll
    for (int p = 0; p < 2; ++p) {
      union { u32x4 u; u16 us[8]; } v;
      v.u = row[p * 64 + lane];
#pragma unroll
      for (int i = 0; i < 8; ++i) {
        float f = __uint_as_float(((unsigned)v.us[i]) << 16) * sc;
        x[p * 8 + i] = f;
        sum += f;
        sq += f * f;
      }
    }
#pragma unroll
    for (int off = 32; off > 0; off >>= 1) {
      sum += __shfl_xor(sum, off, 64);
      sq += __shfl_xor(sq, off, 64);
    }
    const float mean = sum * (1.f / HIDDEN);
    const float var = sq * (1.f / HIDDEN) - mean * mean;
    const float rstd = rsqrtf(var + 1e-5f);
    const float4* g4 = (const float4*)gamma;
    const float4* b4 = (const float4*)beta;
#pragma unroll
    for (int p = 0; p < 2; ++p) {
      int e4 = (p * 64 + lane) * 2;
      float4 gm0 = g4[e4], gm1 = g4[e4 + 1];
      float4 bt0 = b4[e4], bt1 = b4[e4 + 1];
      f32x4 o0, o1;
      o0[0] = (x[p * 8 + 0] - mean) * rstd * gm0.x + bt0.x;
      o0[1] = (x[p * 8 + 1] - mean) * rstd * gm0.y + bt0.y;
      o0[2] = (x[p * 8 + 2] - mean) * rstd * gm0.z + bt0.z;
      o0[3] = (x[p * 8 + 3] - mean) * rstd * gm0.w + bt0.w;
      o1[0] = (x[p * 8 + 4] - mean) * rstd * gm1.x + bt1.x;
      o1[1] = (x[p * 8 + 5] - mean) * rstd * gm1.y + bt1.y;
      o1[2] = (x[p * 8 + 6] - mean) * rstd * gm1.z + bt1.z;
      o1[3] = (x[p * 8 + 7] - mean) * rstd * gm1.w + bt1.w;
      float* op = out + (size_t)tok * HIDDEN + e4 * 4;
      __builtin_nontemporal_store(o0, (f32x4*)op);
      __builtin_nontemporal_store(o1, (f32x4*)(op + 4));
    }
  }
}

// ============ k3 fallback (only if ws too small to host Abf) ============
__global__ __launch_bounds__(256) void k3_ln(const u16* __restrict__ C,
                                             const float* __restrict__ s,
                                             const float* __restrict__ gamma,
                                             const float* __restrict__ beta,
                                             float* __restrict__ out) {
  const int t = threadIdx.x;
  const int lane = t & 63;
  const int tok = blockIdx.x * 4 + (t >> 6);
  const float sc = s[tok];
  const u32x4* row = (const u32x4*)(C + (size_t)tok * HIDDEN);
  float x[16];
  float sum = 0.f, sq = 0.f;
#pragma unroll
  for (int p = 0; p < 2; ++p) {
    union { u32x4 u; u16 us[8]; } v;
    v.u = row[p * 64 + lane];
#pragma unroll
    for (int i = 0; i < 8; ++i) {
      float f = __uint_as_float(((unsigned)v.us[i]) << 16) * sc;
      x[p * 8 + i] = f;
      sum += f;
      sq += f * f;
    }
  }
#pragma unroll
  for (int off = 32; off > 0; off >>= 1) {
    sum += __shfl_xor(sum, off, 64);
    sq += __shfl_xor(sq, off, 64);
  }
  const float mean = sum * (1.f / HIDDEN);
  const float var = sq * (1.f / HIDDEN) - mean * mean;
  const float rstd = rsqrtf(var + 1e-5f);
  const float4* g4 = (const float4*)gamma;
  const float4* b4 = (const float4*)beta;
#pragma unroll
  for (int p = 0; p < 2; ++p) {
    int e4 = (p * 64 + lane) * 2;
    float4 gm0 = g4[e4], gm1 = g4[e4 + 1];
    float4 bt0 = b4[e4], bt1 = b4[e4 + 1];
    f32x4 o0, o1;
    o0[0] = (x[p * 8 + 0] - mean) * rstd * gm0.x + bt0.x;
    o0[1] = (x[p * 8 + 1] - mean) * rstd * gm0.y + bt0.y;
    o0[2] = (x[p * 8 + 2] - mean) * rstd * gm0.z + bt0.z;
    o0[3] = (x[p * 8 + 3] - mean) * rstd * gm0.w + bt0.w;
    o1[0] = (x[p * 8 + 4] - mean) * rstd * gm1.x + bt1.x;
    o1[1] = (x[p * 8 + 5] - mean) * rstd * gm1.y + bt1.y;
    o1[2] = (x[p * 8 + 6] - mean) * rstd * gm1.z + bt1.z;
    o1[3] = (x[p * 8 + 7] - mean) * rstd * gm1.w + bt1.w;
    float* op = out + (size_t)tok * HIDDEN + e4 * 4;
    __builtin_nontemporal_store(o0, (f32x4*)op);
    __builtin_nontemporal_store(o1, (f32x4*)(op + 4));
  }
}

extern "C" void kernel_launch(void* const* d_in, const int* in_sizes, int n_in,
                              void* d_out, int out_size, void* d_ws, size_t ws_size,
                              hipStream_t stream) {
  (void)in_sizes; (void)n_in; (void)out_size;
  const float* H = (const float*)d_in[0];      // [4,8192,1024] fp32
  const float* G = (const float*)d_in[1];      // [8,1024] fp32
  const float* W = (const float*)d_in[2];      // [1024,1024] fp32
  const float* gamma = (const float*)d_in[3];  // [1024]
  const float* beta = (const float*)d_in[4];   // [1024]
  float* out = (float*)d_out;

  char* ws = (char*)d_ws;
  u16* Bt = (u16*)ws;                                         // 2 MiB
  float* s = (float*)(ws + (size_t)(2u << 20));               // 128 KiB
  int* cnt = (int*)(ws + (size_t)(2u << 20) + (128u << 10));  // 512 B
  u16* C = (u16*)(ws + (size_t)(2u << 20) + (256u << 10));    // 64 MiB

  const size_t need = ((size_t)66u << 20) + ((size_t)256u << 10) + ((size_t)64u << 20);
  const int fuse = (ws_size >= need) ? 1 : 0;
  // Abf: in ws when it fits (d_out is written live by kB's LN); else d_out
  // scratch with the separate k3 pass (no aliasing hazard when LN disabled).
  u16* Abf = fuse ? (u16*)(ws + ((size_t)66u << 20) + ((size_t)256u << 10))
                  : (u16*)d_out;

  kA<<<1280, 512, 0, stream>>>(H, G, W, s, Bt, Abf, cnt);
  kB<<<512, 512, 0, stream>>>(Abf, Bt, s, gamma, beta, C, out, cnt, fuse);
  if (!fuse) k3_ln<<<TOKENS / 4, 256, 0, stream>>>(C, s, gamma, beta, out);
}

// Round 6
// 380.405 us; speedup vs baseline: 1.2020x; 1.2020x over previous
//
#include <hip/hip_runtime.h>
#include <hip/hip_bf16.h>
#include <stdint.h>

#define HIDDEN 1024
#define TOKENS 32768
#define NE 8

typedef unsigned short u16;
typedef short bf16x8 __attribute__((ext_vector_type(8)));
typedef float f32x4 __attribute__((ext_vector_type(4)));

__device__ __forceinline__ void gload_lds16(const void* g, void* l) {
  __builtin_amdgcn_global_load_lds(
      (const __attribute__((address_space(1))) void*)g,
      (__attribute__((address_space(3))) void*)l, 16, 0, 0);
}

// ============ kA: fused prep (grid-split) ============
// blocks [0,1024): gating (fp32) -> s[tok]; emit Abf (bf16 H).
// blocks [1024,1280): W transpose+convert -> Bt.
__global__ __launch_bounds__(512) void kA(const float* __restrict__ H,
                                          const float* __restrict__ G,
                                          const float* __restrict__ W,
                                          float* __restrict__ s,
                                          u16* __restrict__ Bt,
                                          u16* __restrict__ Abf) {
  __shared__ float shf[NE * HIDDEN];  // 32 KiB
  const int t = threadIdx.x;

  if (blockIdx.x >= 1024) {
    const int bx = blockIdx.x - 1024;
    const int d0 = (bx & 15) * 64;
    const int h0 = (bx >> 4) * 64;
#pragma unroll
    for (int p = 0; p < 8; ++p) {
      int idx = p * 512 + t;
      int r = idx >> 6, c = idx & 63;
      shf[r * 65 + c] = W[(size_t)(h0 + r) * HIDDEN + d0 + c];
    }
    __syncthreads();
#pragma unroll
    for (int p = 0; p < 8; ++p) {
      int idx = p * 512 + t;
      int r = idx >> 6, c = idx & 63;
      __hip_bfloat16 v = __float2bfloat16(shf[c * 65 + r]);
      Bt[(size_t)(d0 + r) * HIDDEN + h0 + c] = *(u16*)&v;
    }
    return;
  }

#pragma unroll
  for (int i = 0; i < 4; ++i)
    ((float4*)shf)[i * 512 + t] = ((const float4*)G)[i * 512 + t];
  __syncthreads();

  const int lane = t & 63;
  const int wave = t >> 6;
  const int tok0 = (blockIdx.x * 8 + wave) * 4;

#pragma unroll
  for (int tp = 0; tp < 2; ++tp) {
    const int tok = tok0 + tp * 2;
    const float* h0p = H + (size_t)tok * HIDDEN;
    const float* h1p = h0p + HIDDEN;
    float4 h0[4], h1[4];
#pragma unroll
    for (int p = 0; p < 4; ++p) {
      h0[p] = *(const float4*)(h0p + p * 256 + lane * 4);
      h1[p] = *(const float4*)(h1p + p * 256 + lane * 4);
    }
#pragma unroll
    for (int p = 0; p < 4; ++p) {
      __hip_bfloat162 lo0 = __float22bfloat162_rn(make_float2(h0[p].x, h0[p].y));
      __hip_bfloat162 hi0 = __float22bfloat162_rn(make_float2(h0[p].z, h0[p].w));
      uint2 pk0;
      pk0.x = *(unsigned*)&lo0;
      pk0.y = *(unsigned*)&hi0;
      *(uint2*)(Abf + (size_t)tok * HIDDEN + p * 256 + lane * 4) = pk0;
      __hip_bfloat162 lo1 = __float22bfloat162_rn(make_float2(h1[p].x, h1[p].y));
      __hip_bfloat162 hi1 = __float22bfloat162_rn(make_float2(h1[p].z, h1[p].w));
      uint2 pk1;
      pk1.x = *(unsigned*)&lo1;
      pk1.y = *(unsigned*)&hi1;
      *(uint2*)(Abf + (size_t)(tok + 1) * HIDDEN + p * 256 + lane * 4) = pk1;
    }

    float a0[NE], a1[NE];
#pragma unroll
    for (int e = 0; e < NE; ++e) { a0[e] = 0.f; a1[e] = 0.f; }
#pragma unroll
    for (int p = 0; p < 4; ++p)
#pragma unroll
      for (int e = 0; e < NE; ++e) {
        float4 w = *(const float4*)&shf[e * HIDDEN + p * 256 + lane * 4];
        a0[e] += h0[p].x * w.x + h0[p].y * w.y + h0[p].z * w.z + h0[p].w * w.w;
        a1[e] += h1[p].x * w.x + h1[p].y * w.y + h1[p].z * w.z + h1[p].w * w.w;
      }
#pragma unroll
    for (int st = 1; st <= 4; st <<= 1)
#pragma unroll
      for (int e = 0; e < NE; ++e) {
        a0[e] += __shfl_xor(a0[e], st, 64);
        a1[e] += __shfl_xor(a1[e], st, 64);
      }
    const bool b0 = lane & 1, b1 = lane & 2, b2 = lane & 4;
    float t01 = b0 ? a0[1] : a0[0], t23 = b0 ? a0[3] : a0[2];
    float t45 = b0 ? a0[5] : a0[4], t67 = b0 ? a0[7] : a0[6];
    float u03 = b1 ? t23 : t01, u47 = b1 ? t67 : t45;
    float v0 = b2 ? u47 : u03;
    float s01 = b0 ? a1[1] : a1[0], s23 = b0 ? a1[3] : a1[2];
    float s45 = b0 ? a1[5] : a1[4], s67 = b0 ? a1[7] : a1[6];
    float w03 = b1 ? s23 : s01, w47 = b1 ? s67 : s45;
    float v1 = b2 ? w47 : w03;
    v0 += __shfl_xor(v0, 8, 64);
    v0 += __shfl_xor(v0, 16, 64);
    v0 += __shfl_xor(v0, 32, 64);
    v1 += __shfl_xor(v1, 8, 64);
    v1 += __shfl_xor(v1, 16, 64);
    v1 += __shfl_xor(v1, 32, 64);
    float m1a = v0, m2a = -3.0e38f, m1b = v1, m2b = -3.0e38f;
#pragma unroll
    for (int st = 1; st <= 4; st <<= 1) {
      float o1 = __shfl_xor(m1a, st, 64);
      float o2 = __shfl_xor(m2a, st, 64);
      float lo = fminf(m1a, o1);
      m1a = fmaxf(m1a, o1);
      m2a = fmaxf(lo, fmaxf(m2a, o2));
      float p1 = __shfl_xor(m1b, st, 64);
      float p2 = __shfl_xor(m2b, st, 64);
      float lo2 = fminf(m1b, p1);
      m1b = fmaxf(m1b, p1);
      m2b = fmaxf(lo2, fmaxf(m2b, p2));
    }
    if (lane == 0) {
      s[tok] = m1a + m2a;
      s[tok + 1] = m1b + m2b;
    }
  }
}

// ============ kB: full-width GEMM + scale + LayerNorm -> out (fp32) ============
// Block = 64 rows x 1024 cols (full row). 1024 threads = 16 waves (4/SIMD),
// wave tile 64x64 -> acc[4][4] (64 VGPR); hard cap 128 VGPR/thread respected.
// LDS/buf: A 64x32 (4KB) + B 1024x32 (64KB) = 68KB, double-buffered = 136KB.
// B (2 MiB total) is L2-resident across all blocks; A unique per block.
// R2-proven chunk swizzle + counted-vmcnt pipeline (per-wave count 5 or 4).
#define BUFE 34816  // u16 per buffer

__global__ __launch_bounds__(1024, 4) void kB(const u16* __restrict__ A,
                                              const u16* __restrict__ Bt,
                                              const float* __restrict__ s,
                                              const float* __restrict__ gamma,
                                              const float* __restrict__ beta,
                                              float* __restrict__ out) {
  __shared__ u16 smem[2 * BUFE];  // 136 KiB
  const int t = threadIdx.x;
  const int lane = t & 63;
  const int wave = t >> 6;
  const int m0 = blockIdx.x * 64;
  const int wn = wave * 64;
  const int lm = lane & 15;
  const int lq = lane >> 4;

  // staging maps. A: threads t<256 (waves 0-3), 1 chunk; B: all threads, 4 chunks.
  // LDS slot (r,qs) holds global k-chunk q = qs ^ sw(r), sw(r)=(r^(r>>2))&3.
  const bool doA = (t < 256);
  int aoff = 0;
  {
    int r = t >> 2, qs = t & 3;
    int q = qs ^ ((r ^ (r >> 2)) & 3);
    aoff = (m0 + (r & 63)) * HIDDEN + q * 8;
  }
  int boff[4];
#pragma unroll
  for (int m = 0; m < 4; ++m) {
    int bq = t + m * 1024, r = bq >> 2, qs = bq & 3;
    int q = qs ^ ((r ^ (r >> 2)) & 3);
    boff[m] = r * HIDDEN + q * 8;
  }

#define STAGE(buf, kt)                                                  \
  do {                                                                  \
    u16* bs_ = smem + (buf) * BUFE;                                     \
    if (doA) gload_lds16(A + aoff + (kt) * 32, bs_ + t * 8);            \
    _Pragma("unroll") for (int m_ = 0; m_ < 4; ++m_)                    \
        gload_lds16(Bt + boff[m_] + (kt) * 32,                          \
                    bs_ + 2048 + (t + m_ * 1024) * 8);                  \
  } while (0)

#define WAITC()                                                         \
  do {                                                                  \
    if (wave < 4) asm volatile("s_waitcnt vmcnt(5)" ::: "memory");      \
    else          asm volatile("s_waitcnt vmcnt(4)" ::: "memory");      \
  } while (0)

  f32x4 acc[4][4];
#pragma unroll
  for (int i = 0; i < 4; ++i)
#pragma unroll
    for (int j = 0; j < 4; ++j) acc[i][j] = (f32x4){0.f, 0.f, 0.f, 0.f};

  STAGE(0, 0);
  STAGE(1, 1);
  WAITC();
  asm volatile("s_barrier" ::: "memory");

  for (int tt = 0; tt < 32; ++tt) {
    const u16* As = smem + (tt & 1) * BUFE;
    bf16x8 af[4], bfr[4];
#pragma unroll
    for (int i = 0; i < 4; ++i) {
      int r = i * 16 + lm;
      int qs = lq ^ ((r ^ (r >> 2)) & 3);
      af[i] = *(const bf16x8*)&As[(r * 4 + qs) * 8];
    }
#pragma unroll
    for (int j = 0; j < 4; ++j) {
      int n = wn + j * 16 + lm;
      int qs = lq ^ ((n ^ (n >> 2)) & 3);
      bfr[j] = *(const bf16x8*)&As[2048 + (n * 4 + qs) * 8];
    }
    __builtin_amdgcn_s_setprio(1);
#pragma unroll
    for (int i = 0; i < 4; ++i)
#pragma unroll
      for (int j = 0; j < 4; ++j)
        acc[i][j] = __builtin_amdgcn_mfma_f32_16x16x32_bf16(af[i], bfr[j], acc[i][j], 0, 0, 0);
    __builtin_amdgcn_s_setprio(0);
    asm volatile("s_waitcnt lgkmcnt(0)" ::: "memory");
    asm volatile("s_barrier" ::: "memory");
    if (tt + 2 < 32) {
      STAGE(tt & 1, tt + 2);
      WAITC();
    } else {
      asm volatile("s_waitcnt vmcnt(0)" ::: "memory");
    }
    asm volatile("s_barrier" ::: "memory");
  }
#undef STAGE
#undef WAITC

  // ---- fused epilogue: x = s[row]*acc; LN over the full 1024-wide row.
  float* S = (float*)smem;          // [64 rows][16 waves][2] = 8 KiB
  float* R = (float*)smem + 2048;   // [64][2] mean/rstd

#pragma unroll
  for (int i = 0; i < 4; ++i) {
#pragma unroll
    for (int rr = 0; rr < 4; ++rr) {
      const int row = i * 16 + lq * 4 + rr;
      const float sc = s[m0 + row];
      float ps = 0.f, pq = 0.f;
#pragma unroll
      for (int j = 0; j < 4; ++j) {
        float v = acc[i][j][rr] * sc;
        acc[i][j][rr] = v;
        ps += v;
        pq += v * v;
      }
#pragma unroll
      for (int off = 1; off <= 8; off <<= 1) {
        ps += __shfl_xor(ps, off, 64);
        pq += __shfl_xor(pq, off, 64);
      }
      if (lm == 0) {
        S[(row * 16 + wave) * 2] = ps;
        S[(row * 16 + wave) * 2 + 1] = pq;
      }
    }
  }
  __syncthreads();
  if (t < 64) {
    float ssum = 0.f, ssq = 0.f;
#pragma unroll
    for (int w = 0; w < 16; ++w) {
      ssum += S[(t * 16 + w) * 2];
      ssq += S[(t * 16 + w) * 2 + 1];
    }
    float mean = ssum * (1.f / HIDDEN);
    float var = ssq * (1.f / HIDDEN) - mean * mean;
    R[t * 2] = mean;
    R[t * 2 + 1] = rsqrtf(var + 1e-5f);
  }
  __syncthreads();
  float gj[4], bj[4];
#pragma unroll
  for (int j = 0; j < 4; ++j) {
    gj[j] = gamma[wn + j * 16 + lm];
    bj[j] = beta[wn + j * 16 + lm];
  }
#pragma unroll
  for (int i = 0; i < 4; ++i) {
#pragma unroll
    for (int rr = 0; rr < 4; ++rr) {
      const int row = i * 16 + lq * 4 + rr;
      const float mean = R[row * 2];
      const float rstd = R[row * 2 + 1];
      float* op = out + (size_t)(m0 + row) * HIDDEN + wn + lm;
#pragma unroll
      for (int j = 0; j < 4; ++j)
        __builtin_nontemporal_store((acc[i][j][rr] - mean) * rstd * gj[j] + bj[j],
                                    op + j * 16);
    }
  }
}

extern "C" void kernel_launch(void* const* d_in, const int* in_sizes, int n_in,
                              void* d_out, int out_size, void* d_ws, size_t ws_size,
                              hipStream_t stream) {
  (void)in_sizes; (void)n_in; (void)out_size; (void)ws_size;
  const float* H = (const float*)d_in[0];      // [4,8192,1024] fp32
  const float* G = (const float*)d_in[1];      // [8,1024] fp32
  const float* W = (const float*)d_in[2];      // [1024,1024] fp32
  const float* gamma = (const float*)d_in[3];  // [1024]
  const float* beta = (const float*)d_in[4];   // [1024]
  float* out = (float*)d_out;

  char* ws = (char*)d_ws;
  u16* Bt = (u16*)ws;                                          // 2 MiB
  float* s = (float*)(ws + (size_t)(2u << 20));                // 128 KiB
  u16* Abf = (u16*)(ws + (size_t)(2u << 20) + (256u << 10));   // 64 MiB

  kA<<<1280, 512, 0, stream>>>(H, G, W, s, Bt, Abf);
  kB<<<TOKENS / 64, 1024, 0, stream>>>(Abf, Bt, s, gamma, beta, out);
}